// Round 1
// baseline (336.458 us; speedup 1.0000x reference)
//
#include <hip/hip_runtime.h>

#define NV 16384
#define RPW 8        // rows of L per wave
#define WAVES 4      // waves per block
#define THREADS (WAVES * 64)

__global__ __launch_bounds__(THREADS) void lap_loss_kernel(
    const float* __restrict__ x, const float* __restrict__ L,
    float* __restrict__ out) {
  const int lane = threadIdx.x & 63;
  const int wid  = blockIdx.x * WAVES + (threadIdx.x >> 6);
  const int i0   = wid * RPW;

  float acc[RPW][12];
#pragma unroll
  for (int r = 0; r < RPW; ++r)
#pragma unroll
    for (int k = 0; k < 12; ++k) acc[r][k] = 0.f;

  const float* Lrow = L + (size_t)i0 * NV;

#pragma unroll 1
  for (int jb = 0; jb < NV; jb += 64) {
    const int j = jb + lane;

    // x[b][j][0..2] for b = 0..3 — contiguous 12B per (b,j), L2-resident
    float xv[12];
#pragma unroll
    for (int b = 0; b < 4; ++b) {
      const float* xp = x + ((size_t)b * NV + j) * 3;
      xv[b * 3 + 0] = xp[0];
      xv[b * 3 + 1] = xp[1];
      xv[b * 3 + 2] = xp[2];
    }

    // 8 coalesced row-streams of L
    float lv[RPW];
#pragma unroll
    for (int r = 0; r < RPW; ++r) lv[r] = Lrow[(size_t)r * NV + j];

#pragma unroll
    for (int r = 0; r < RPW; ++r)
#pragma unroll
      for (int k = 0; k < 12; ++k)
        acc[r][k] = fmaf(lv[r], xv[k], acc[r][k]);
  }

  // Cross-lane butterfly reduction of each partial dot product, then square.
  float s[4] = {0.f, 0.f, 0.f, 0.f};
#pragma unroll
  for (int r = 0; r < RPW; ++r)
#pragma unroll
    for (int k = 0; k < 12; ++k) {
      float v = acc[r][k];
#pragma unroll
      for (int off = 32; off > 0; off >>= 1)
        v += __shfl_xor(v, off, 64);
      s[k / 3] += v * v;  // all lanes compute identical total; lane 0 commits
    }

  if (lane == 0) {
#pragma unroll
    for (int b = 0; b < 4; ++b) atomicAdd(&out[b], s[b]);
  }
}

extern "C" void kernel_launch(void* const* d_in, const int* in_sizes, int n_in,
                              void* d_out, int out_size, void* d_ws, size_t ws_size,
                              hipStream_t stream) {
  const float* x = (const float*)d_in[0];
  const float* L = (const float*)d_in[1];
  float* out = (float*)d_out;

  // Harness poisons d_out with 0xAA and never re-poisons between replays.
  hipMemsetAsync(out, 0, out_size * sizeof(float), stream);

  const int nwaves  = NV / RPW;          // 2048
  const int nblocks = nwaves / WAVES;    // 512
  lap_loss_kernel<<<nblocks, THREADS, 0, stream>>>(x, L, out);
}